// Round 5
// baseline (142.535 us; speedup 1.0000x reference)
//
#include <hip/hip_runtime.h>

#define IH 4096
#define IW 4096
#define KH 16
#define KW 16
#define OH 4081
#define OW 4081

#define TBR 64        // output rows per block
#define TBC 128       // output cols per block
#define LROWS 79      // TBR + 15
#define LSTR 168      // shorts per LDS row = 336 B; odd 16B-chunk count -> bank
                      // rotation: row base bank advances 20 mod 32, all 8 quads
                      // covered every 8 rows -> conflict-free b128, no XOR.

typedef short bf16x8 __attribute__((ext_vector_type(8)));
typedef float f32x16 __attribute__((ext_vector_type(16)));

static __device__ __forceinline__ unsigned int f2bf(float f) {
    unsigned int u = __float_as_uint(f);
    return (u + 0x7FFFu + ((u >> 16) & 1u)) >> 16;   // RTNE
}

// Bt[(u*32 + n)*48 + vp] = w[u][vp - n] if 0 <= vp-n < 16 else 0   (48 KB)
__global__ void build_B(const float* __restrict__ wgt, unsigned short* __restrict__ Bt) {
    int idx = blockIdx.x * 256 + threadIdx.x;        // 0..24575
    if (idx >= 16 * 32 * 48) return;
    int vp = idx % 48;
    int n  = (idx / 48) & 31;
    int u  = idx / (48 * 32);
    int t  = vp - n;
    float val = (t >= 0 && t < KW) ? wgt[u * KW + t] : 0.0f;
    Bt[idx] = (unsigned short)f2bf(val);
}

__global__ __launch_bounds__(256, 6)
void conv_mfma32(const float* __restrict__ x,
                 const unsigned short* __restrict__ Bt,
                 const float* __restrict__ bias,
                 float* __restrict__ out) {
    __shared__ unsigned short tile[LROWS * LSTR];    // 26544 B -> 6 blocks/CU

    const int tid  = threadIdx.x;
    const int lane = tid & 63;
    const int wv   = tid >> 6;       // 0..3
    const int rb   = wv >> 1;        // wave row-block (32 rows)
    const int cb   = wv & 1;         // wave col-block (64 cols)
    const int m    = lane & 31;      // A row m / B col n / C col
    const int hi   = lane >> 5;      // k-half select
    const int gy0  = blockIdx.y * TBR;
    const int gx0  = blockIdx.x * TBC;

    // ---- stage 79 x 144 fp32 -> bf16 LDS, one b128 write per 8 cols ----
    for (int idx = tid; idx < LROWS * 18; idx += 256) {
        int row = idx / 18;
        int c   = idx - row * 18;    // 8-col chunk
        int gy  = gy0 + row;
        int gx  = gx0 + 8 * c;
        float4 q0 = make_float4(0.f, 0.f, 0.f, 0.f);
        float4 q1 = q0;
        if (gy < IH && gx < IW) {    // gx%8==0, IW%8==0 -> both halves in or out
            q0 = *reinterpret_cast<const float4*>(x + (size_t)gy * IW + gx);
            q1 = *reinterpret_cast<const float4*>(x + (size_t)gy * IW + gx + 4);
        }
        uint4 p;
        p.x = f2bf(q0.x) | (f2bf(q0.y) << 16);
        p.y = f2bf(q0.z) | (f2bf(q0.w) << 16);
        p.z = f2bf(q1.x) | (f2bf(q1.y) << 16);
        p.w = f2bf(q1.z) | (f2bf(q1.w) << 16);
        *reinterpret_cast<uint4*>(&tile[row * LSTR + c * 8]) = p;
    }
    __syncthreads();

    // ---- main: wave = 32 rows x 2 col-groups(32); K=48 band per u ----
    f32x16 acc0 = {0,0,0,0,0,0,0,0,0,0,0,0,0,0,0,0};
    f32x16 acc1 = {0,0,0,0,0,0,0,0,0,0,0,0,0,0,0,0};

    const int cB = cb * 8 + hi;      // lane's base 16B-chunk
    const unsigned short* Blane = Bt + m * 48 + hi * 8;

    // B register double-buffer, prefetch distance 1
    bf16x8 bc0 = *reinterpret_cast<const bf16x8*>(Blane + 0);
    bf16x8 bc1 = *reinterpret_cast<const bf16x8*>(Blane + 16);
    bf16x8 bc2 = *reinterpret_cast<const bf16x8*>(Blane + 32);

#pragma unroll
    for (int u = 0; u < KH; ++u) {
        bf16x8 bn0 = bc0, bn1 = bc1, bn2 = bc2;
        if (u + 1 < KH) {
            const unsigned short* Bu = Blane + (u + 1) * (32 * 48);
            bn0 = *reinterpret_cast<const bf16x8*>(Bu + 0);
            bn1 = *reinterpret_cast<const bf16x8*>(Bu + 16);
            bn2 = *reinterpret_cast<const bf16x8*>(Bu + 32);
        }

        const int rowA = rb * 32 + m + u;            // 0..78
        const unsigned short* rbase = &tile[rowA * LSTR];

        bf16x8 a0 = *reinterpret_cast<const bf16x8*>(rbase + (cB + 0) * 8);
        bf16x8 a1 = *reinterpret_cast<const bf16x8*>(rbase + (cB + 2) * 8);
        bf16x8 a2 = *reinterpret_cast<const bf16x8*>(rbase + (cB + 4) * 8);
        bf16x8 a3 = *reinterpret_cast<const bf16x8*>(rbase + (cB + 6) * 8);
        bf16x8 a4 = *reinterpret_cast<const bf16x8*>(rbase + (cB + 8) * 8);

        acc0 = __builtin_amdgcn_mfma_f32_32x32x16_bf16(a0, bc0, acc0, 0, 0, 0);
        acc0 = __builtin_amdgcn_mfma_f32_32x32x16_bf16(a1, bc1, acc0, 0, 0, 0);
        acc0 = __builtin_amdgcn_mfma_f32_32x32x16_bf16(a2, bc2, acc0, 0, 0, 0);
        acc1 = __builtin_amdgcn_mfma_f32_32x32x16_bf16(a2, bc0, acc1, 0, 0, 0);
        acc1 = __builtin_amdgcn_mfma_f32_32x32x16_bf16(a3, bc1, acc1, 0, 0, 0);
        acc1 = __builtin_amdgcn_mfma_f32_32x32x16_bf16(a4, bc2, acc1, 0, 0, 0);

        bc0 = bn0; bc1 = bn1; bc2 = bn2;
    }

    // ---- epilogue: C/D col=lane&31, row=(reg&3)+8*(reg>>2)+4*hi ----
    const float bv   = bias[0];
    const int   row0 = gy0 + rb * 32 + 4 * hi;
    const int   col0 = gx0 + cb * 64 + m;
    const bool  full = (gy0 + TBR <= OH) && (gx0 + TBC <= OW);

#pragma unroll
    for (int g = 0; g < 2; ++g) {
        const f32x16 acc = g ? acc1 : acc0;
        const int col = col0 + g * 32;
        float* op = out + col;
        if (full) {
#pragma unroll
            for (int r = 0; r < 16; ++r) {
                int rr = row0 + (r & 3) + 8 * (r >> 2);
                op[(size_t)rr * OW] = acc[r] + bv;
            }
        } else if (col < OW) {
#pragma unroll
            for (int r = 0; r < 16; ++r) {
                int rr = row0 + (r & 3) + 8 * (r >> 2);
                if (rr < OH) op[(size_t)rr * OW] = acc[r] + bv;
            }
        }
    }
}

extern "C" void kernel_launch(void* const* d_in, const int* in_sizes, int n_in,
                              void* d_out, int out_size, void* d_ws, size_t ws_size,
                              hipStream_t stream) {
    const float* x  = (const float*)d_in[0];
    const float* w  = (const float*)d_in[1];
    const float* b  = (const float*)d_in[2];
    float* out = (float*)d_out;
    unsigned short* Bt = (unsigned short*)d_ws;

    build_B<<<96, 256, 0, stream>>>(w, Bt);

    dim3 grid((OW + TBC - 1) / TBC, (OH + TBR - 1) / TBR);  // 32 x 64
    conv_mfma32<<<grid, dim3(256), 0, stream>>>(x, Bt, b, out);
}

// Round 6
// 137.264 us; speedup vs baseline: 1.0384x; 1.0384x over previous
//
#include <hip/hip_runtime.h>

#define IH 4096
#define IW 4096
#define KH 16
#define KW 16
#define OH 4081
#define OW 4081

#define TBR 64        // output rows per block
#define TBC 128       // output cols per block
#define LROWS 79      // TBR + 15
#define LSTR 168      // shorts per LDS row = 336 B; odd 16B-chunk count -> bank
                      // rotation covers all 8 quads every 8 rows -> conflict-free b128.

typedef short bf16x8 __attribute__((ext_vector_type(8)));
typedef float f32x16 __attribute__((ext_vector_type(16)));

static __device__ __forceinline__ unsigned int f2bf(float f) {
    unsigned int u = __float_as_uint(f);
    return (u + 0x7FFFu + ((u >> 16) & 1u)) >> 16;   // RTNE
}

// Coalesced B layout: Bt[(u*3 + c)*512 + lane*8 + j], lane = hi*32 + n,
// value = w[u][vp - n] with vp = c*16 + hi*8 + j  (0 outside band). 48 KB.
// A wave (lanes 0..63) reading chunk (u,c) touches contiguous 1024 B.
__global__ void build_B(const float* __restrict__ wgt, unsigned short* __restrict__ Bt) {
    int idx = blockIdx.x * 256 + threadIdx.x;        // 0..24575
    if (idx >= 16 * 3 * 512) return;
    int j    = idx & 7;
    int lane = (idx >> 3) & 63;
    int n    = lane & 31;
    int hi   = lane >> 5;
    int c    = (idx >> 9) % 3;
    int u    = idx / 1536;
    int vp   = c * 16 + hi * 8 + j;
    int t    = vp - n;
    float val = (t >= 0 && t < KW) ? wgt[u * KW + t] : 0.0f;
    Bt[idx] = (unsigned short)f2bf(val);
}

__global__ __launch_bounds__(256, 6)
void conv_mfma32(const float* __restrict__ x,
                 const unsigned short* __restrict__ Bt,
                 const float* __restrict__ bias,
                 float* __restrict__ out) {
    __shared__ unsigned short tile[LROWS * LSTR];    // 26544 B -> 6 blocks/CU

    const int tid  = threadIdx.x;
    const int lane = tid & 63;
    const int wv   = tid >> 6;       // 0..3
    const int rb   = wv >> 1;        // wave row-block (32 rows)
    const int cb   = wv & 1;         // wave col-block (64 cols)
    const int m    = lane & 31;      // A row m / B col n / C col
    const int hi   = lane >> 5;      // k-half select
    const int gy0  = blockIdx.y * TBR;
    const int gx0  = blockIdx.x * TBC;

    // ---- stage 79 x 144 fp32 -> bf16 LDS, one b128 write per 8 cols ----
    for (int idx = tid; idx < LROWS * 18; idx += 256) {
        int row = idx / 18;
        int c   = idx - row * 18;    // 8-col chunk
        int gy  = gy0 + row;
        int gx  = gx0 + 8 * c;
        float4 q0 = make_float4(0.f, 0.f, 0.f, 0.f);
        float4 q1 = q0;
        if (gy < IH && gx < IW) {    // gx%8==0, IW%8==0 -> both halves in or out
            q0 = *reinterpret_cast<const float4*>(x + (size_t)gy * IW + gx);
            q1 = *reinterpret_cast<const float4*>(x + (size_t)gy * IW + gx + 4);
        }
        uint4 p;
        p.x = f2bf(q0.x) | (f2bf(q0.y) << 16);
        p.y = f2bf(q0.z) | (f2bf(q0.w) << 16);
        p.z = f2bf(q1.x) | (f2bf(q1.y) << 16);
        p.w = f2bf(q1.z) | (f2bf(q1.w) << 16);
        *reinterpret_cast<uint4*>(&tile[row * LSTR + c * 8]) = p;
    }
    __syncthreads();

    // ---- main: wave = 32 rows x 2 col-groups(32); K=48 band per u ----
    f32x16 acc0 = {0,0,0,0,0,0,0,0,0,0,0,0,0,0,0,0};
    f32x16 acc1 = {0,0,0,0,0,0,0,0,0,0,0,0,0,0,0,0};

    const int cB = cb * 8 + hi;      // lane's base 16B-chunk in x-tile row
    const unsigned short* Blane = Bt + lane * 8;   // wave-contiguous 1 KB fetches

    // B register double-buffer, prefetch distance 1
    bf16x8 bc0 = *reinterpret_cast<const bf16x8*>(Blane + 0);
    bf16x8 bc1 = *reinterpret_cast<const bf16x8*>(Blane + 512);
    bf16x8 bc2 = *reinterpret_cast<const bf16x8*>(Blane + 1024);

#pragma unroll
    for (int u = 0; u < KH; ++u) {
        bf16x8 bn0 = bc0, bn1 = bc1, bn2 = bc2;
        if (u + 1 < KH) {
            const unsigned short* Bu = Blane + (u + 1) * 1536;
            bn0 = *reinterpret_cast<const bf16x8*>(Bu + 0);
            bn1 = *reinterpret_cast<const bf16x8*>(Bu + 512);
            bn2 = *reinterpret_cast<const bf16x8*>(Bu + 1024);
        }

        const int rowA = rb * 32 + m + u;            // 0..78
        const unsigned short* rbase = &tile[rowA * LSTR];

        bf16x8 a0 = *reinterpret_cast<const bf16x8*>(rbase + (cB + 0) * 8);
        bf16x8 a1 = *reinterpret_cast<const bf16x8*>(rbase + (cB + 2) * 8);
        bf16x8 a2 = *reinterpret_cast<const bf16x8*>(rbase + (cB + 4) * 8);
        bf16x8 a3 = *reinterpret_cast<const bf16x8*>(rbase + (cB + 6) * 8);
        bf16x8 a4 = *reinterpret_cast<const bf16x8*>(rbase + (cB + 8) * 8);

        acc0 = __builtin_amdgcn_mfma_f32_32x32x16_bf16(a0, bc0, acc0, 0, 0, 0);
        acc0 = __builtin_amdgcn_mfma_f32_32x32x16_bf16(a1, bc1, acc0, 0, 0, 0);
        acc0 = __builtin_amdgcn_mfma_f32_32x32x16_bf16(a2, bc2, acc0, 0, 0, 0);
        acc1 = __builtin_amdgcn_mfma_f32_32x32x16_bf16(a2, bc0, acc1, 0, 0, 0);
        acc1 = __builtin_amdgcn_mfma_f32_32x32x16_bf16(a3, bc1, acc1, 0, 0, 0);
        acc1 = __builtin_amdgcn_mfma_f32_32x32x16_bf16(a4, bc2, acc1, 0, 0, 0);

        bc0 = bn0; bc1 = bn1; bc2 = bn2;
    }

    // ---- epilogue: C/D col=lane&31, row=(reg&3)+8*(reg>>2)+4*hi ----
    const float bv   = bias[0];
    const int   row0 = gy0 + rb * 32 + 4 * hi;
    const int   col0 = gx0 + cb * 64 + m;
    const bool  full = (gy0 + TBR <= OH) && (gx0 + TBC <= OW);

#pragma unroll
    for (int g = 0; g < 2; ++g) {
        const f32x16 acc = g ? acc1 : acc0;
        const int col = col0 + g * 32;
        float* op = out + col;
        if (full) {
#pragma unroll
            for (int r = 0; r < 16; ++r) {
                int rr = row0 + (r & 3) + 8 * (r >> 2);
                op[(size_t)rr * OW] = acc[r] + bv;
            }
        } else if (col < OW) {
#pragma unroll
            for (int r = 0; r < 16; ++r) {
                int rr = row0 + (r & 3) + 8 * (r >> 2);
                if (rr < OH) op[(size_t)rr * OW] = acc[r] + bv;
            }
        }
    }
}

extern "C" void kernel_launch(void* const* d_in, const int* in_sizes, int n_in,
                              void* d_out, int out_size, void* d_ws, size_t ws_size,
                              hipStream_t stream) {
    const float* x  = (const float*)d_in[0];
    const float* w  = (const float*)d_in[1];
    const float* b  = (const float*)d_in[2];
    float* out = (float*)d_out;
    unsigned short* Bt = (unsigned short*)d_ws;

    build_B<<<96, 256, 0, stream>>>(w, Bt);

    dim3 grid((OW + TBC - 1) / TBC, (OH + TBR - 1) / TBR);  // 32 x 64
    conv_mfma32<<<grid, dim3(256), 0, stream>>>(x, Bt, b, out);
}